// Round 6
// baseline (180.584 us; speedup 1.0000x reference)
//
#include <hip/hip_runtime.h>
#include <stdint.h>

typedef signed char i8;
typedef __attribute__((ext_vector_type(4))) float f32x4;
typedef __attribute__((ext_vector_type(4))) int i32x4;
typedef __attribute__((ext_vector_type(16))) int i32x16;

#define XSCALE 32.0f
#define INV_XSCALE (1.0f / 32.0f)

// ---------------- conversion kernels ----------------

__device__ __forceinline__ int q8(float f) {
  float s = rintf(f * XSCALE);
  s = fminf(fmaxf(s, -127.0f), 127.0f);
  return ((int)s) & 0xff;
}

// x fp32 -> i8 (scale 32), 16 elems/thread
__global__ __launch_bounds__(256) void cvt_x_kernel(const float* __restrict__ x,
                                                    i32x4* __restrict__ o, int n16) {
  int i = blockIdx.x * blockDim.x + threadIdx.x;
  int stride = gridDim.x * blockDim.x;
  for (; i < n16; i += stride) {
    const f32x4* p = (const f32x4*)x + (size_t)i * 4;
    f32x4 v0 = p[0], v1 = p[1], v2 = p[2], v3 = p[3];
    i32x4 r;
    r[0] = q8(v0[0]) | (q8(v0[1]) << 8) | (q8(v0[2]) << 16) | (q8(v0[3]) << 24);
    r[1] = q8(v1[0]) | (q8(v1[1]) << 8) | (q8(v1[2]) << 16) | (q8(v1[3]) << 24);
    r[2] = q8(v2[0]) | (q8(v2[1]) << 8) | (q8(v2[2]) << 16) | (q8(v2[3]) << 24);
    r[3] = q8(v3[0]) | (q8(v3[1]) << 8) | (q8(v3[2]) << 16) | (q8(v3[3]) << 24);
    o[i] = r;
  }
}

__device__ __forceinline__ int sg8(float f) {
  return (f > 0.0f ? 1 : (f < 0.0f ? -1 : 0)) & 0xff;
}

// w fp32 -> sign i8 (+1/-1/0), 16 elems/thread
__global__ __launch_bounds__(256) void cvt_w_kernel(const float* __restrict__ w,
                                                    i32x4* __restrict__ o, int n16) {
  int i = blockIdx.x * blockDim.x + threadIdx.x;
  int stride = gridDim.x * blockDim.x;
  for (; i < n16; i += stride) {
    const f32x4* p = (const f32x4*)w + (size_t)i * 4;
    f32x4 v0 = p[0], v1 = p[1], v2 = p[2], v3 = p[3];
    i32x4 r;
    r[0] = sg8(v0[0]) | (sg8(v0[1]) << 8) | (sg8(v0[2]) << 16) | (sg8(v0[3]) << 24);
    r[1] = sg8(v1[0]) | (sg8(v1[1]) << 8) | (sg8(v1[2]) << 16) | (sg8(v1[3]) << 24);
    r[2] = sg8(v2[0]) | (sg8(v2[1]) << 8) | (sg8(v2[2]) << 16) | (sg8(v2[3]) << 24);
    r[3] = sg8(v3[0]) | (sg8(v3[1]) << 8) | (sg8(v3[2]) << 16) | (sg8(v3[3]) << 24);
    o[i] = r;
  }
}

// ---------------- 256x256 i8 MFMA GEMM -- 32x32x32 shape, r18 schedule ----
// r19: ONE variable vs r18 -- the MFMA shape. Six structures (2-barrier,
// 1-barrier, 16-wave, B-direct, m201 8-phase) all land at 160-168us with
// MfmaUtil ~35-37 and NO pipe above 40%: the cost scales with neither
// schedule nor occupancy. Remaining invariant: 32x v_mfma_i32_16x16x64_i8
// per wave-tile. Hypothesis: per-INSTRUCTION cost off the throughput books
// (wave issue-slot gap / operand fetch at 2 waves/SIMD; ubench used 8).
// 32x32x32_i8 halves instruction count at +12% rate (4404 vs 3944 TOPS),
// same bytes read, same LDS image/stage/swizzle/phases/vmcnt as r18, same
// acc total (8 frags x 16 i32 = 128). If dur unchanged and MfmaUtil drops
// to ~33, the instruction-cost hypothesis is dead too (clean null).
//
// 32x32 frag addressing (lane l): A[row=l&31][kchunk=(l>>5)*16]; with the
// stage involution (16B chunks within each 64B row XOR'd by (row>>1)&3):
//   addr = rowbase*64 + ((chunk ^ ((l&31)>>1)&3) << 4);  ks flips bit 5.
// Bank check: 256 bank-accesses per b128, exactly 8 per bank -> conflict-
// free. C/D: col=lane&31, row=(reg&3)+8*(reg>>2)+4*(lane>>5) [m74/m101].

__device__ __forceinline__ void load_lds16(const void* g, void* l) {
  __builtin_amdgcn_global_load_lds(
      (const __attribute__((address_space(1))) void*)g,
      (__attribute__((address_space(3))) void*)l,
      16, 0, 0);
}

// stage one 8KB unit (128 rows x 64 cols i8) of a [256][64] sub-tile.
__device__ __forceinline__ void stage_unit(const i8* __restrict__ Gp, int K, int k0,
                                           i8* __restrict__ Tlds, int u, int wave,
                                           int lane) {
  const int base = u * 8192 + wave * 1024;        // physical byte base (wave-uniform)
  const int PA = base + lane * 16;                // this lane's physical bytes
  const int L = PA ^ (((PA >> 7) & 3) << 4);      // logical bytes (involution)
  const int r = L >> 6;                           // tile row (64 i8 per row)
  const int c = L & 63;                           // tile col (16-aligned)
  load_lds16(Gp + (size_t)r * K + k0 + c, Tlds + base);
}

#define BAR __builtin_amdgcn_s_barrier()
#define SGB __builtin_amdgcn_sched_barrier(0)
#define WAITL0 asm volatile("s_waitcnt lgkmcnt(0)" ::: "memory")
#define VMCNT4 asm volatile("s_waitcnt vmcnt(4)" ::: "memory")
#define VMCNT0 asm volatile("s_waitcnt vmcnt(0)" ::: "memory")

// sub-tile byte offsets inside one 64KB buffer:
//   A(s) at s*16384, B(s) at 32768 + s*16384; each [256 rows][64 cols].
// abase/bbase include the swizzled k-chunk for ks=0; ks=1 XORs bit 5.
#define READ_A32(CUR, S, KS)                                                    \
  _Pragma("unroll") for (int mi = 0; mi < 4; ++mi)                              \
    Af[mi] = *(const i32x4*)((CUR) + (S) * 16384 +                              \
                             (abase ^ ((KS) << 5)) + mi * 2048);

#define READ_B32(CUR, S, KS)                                                    \
  _Pragma("unroll") for (int ni = 0; ni < 2; ++ni)                              \
    Bf[ni] = *(const i32x4*)((CUR) + 32768 + (S) * 16384 +                      \
                             (bbase ^ ((KS) << 5)) + ni * 2048);

#define CLUSTER32                                                               \
  __builtin_amdgcn_s_setprio(1);                                                \
  _Pragma("unroll") for (int mi = 0; mi < 4; ++mi)                              \
  _Pragma("unroll") for (int ni = 0; ni < 2; ++ni)                              \
    acc[mi][ni] = __builtin_amdgcn_mfma_i32_32x32x32_i8(                        \
        Af[mi], Bf[ni], acc[mi][ni], 0, 0, 0);                                  \
  __builtin_amdgcn_s_setprio(0);

// One iter = K-slab of 128, 4 phases (2 s-halves x 2 ks-slices), 8 MFMA
// per phase per wave. Stage slots p0:A(s0) p1:B(s0) p2:A(s1) p3:B(s1);
// counted VMCNT4 at p1/p3 only (never 0 in steady state; tail tightens).
#define DO_ITER(t, CUR, NXT)                                                    \
  {                                                                             \
    const int k1 = ((t) + 1) * 128;                                             \
    const bool st = (t) + 1 < NTI;                                              \
    /* ---- p0: (s0, ks0) ---- */                                               \
    READ_A32(CUR, 0, 0); READ_B32(CUR, 0, 0);                                   \
    if (st) { stage_unit(GA, K, k1, NXT, 0, wave, lane);                        \
              stage_unit(GA, K, k1, NXT, 1, wave, lane); }                      \
    BAR; WAITL0; SGB;                                                           \
    CLUSTER32; SGB;                                                             \
    BAR;                                                                        \
    /* ---- p1: (s0, ks1) ---- */                                               \
    READ_A32(CUR, 0, 1); READ_B32(CUR, 0, 1);                                   \
    if (st) { stage_unit(GB, K, k1, NXT + 32768, 0, wave, lane);                \
              stage_unit(GB, K, k1, NXT + 32768, 1, wave, lane);                \
              VMCNT4; } else { VMCNT0; }                                        \
    BAR; WAITL0; SGB;                                                           \
    CLUSTER32; SGB;                                                             \
    BAR;                                                                        \
    /* ---- p2: (s1, ks0) ---- */                                               \
    READ_A32(CUR, 1, 0); READ_B32(CUR, 1, 0);                                   \
    if (st) { stage_unit(GA, K, k1 + 64, NXT + 16384, 0, wave, lane);           \
              stage_unit(GA, K, k1 + 64, NXT + 16384, 1, wave, lane); }         \
    BAR; WAITL0; SGB;                                                           \
    CLUSTER32; SGB;                                                             \
    BAR;                                                                        \
    /* ---- p3: (s1, ks1) ---- */                                               \
    READ_A32(CUR, 1, 1); READ_B32(CUR, 1, 1);                                   \
    if (st) { stage_unit(GB, K, k1 + 64, NXT + 49152, 0, wave, lane);           \
              stage_unit(GB, K, k1 + 64, NXT + 49152, 1, wave, lane);           \
              VMCNT4; } else { VMCNT0; }                                        \
    BAR; WAITL0; SGB;                                                           \
    CLUSTER32; SGB;                                                             \
    BAR;                                                                        \
  }

__global__ __launch_bounds__(512, 2) void bingemm256_kernel(
    const i8* __restrict__ A,      // [M][K] i8 (x * 32)
    const i8* __restrict__ B,      // [N][K] i8 sign
    const float* __restrict__ alpha,
    const float* __restrict__ bias,
    float* __restrict__ C,         // [M][N] fp32
    int M, int N, int K) {
  __shared__ i8 SM[2][65536];      // dbuf x {A s0, A s1, B s0, B s1} = 128 KB

  const int tid = threadIdx.x;
  const int lane = tid & 63;
  const int wave = tid >> 6;  // 0..7
  const int wm = wave >> 2;   // 0..1 (128-row slab)
  const int wn = wave & 3;    // 0..3 (64-col slab)
  const int l31 = lane & 31;
  const int l5 = lane >> 5;   // 0..1

  // XCD-aware swizzle (grid divisible by 8 -> simple bijection)
  const int nwg = gridDim.x;
  const int wg = blockIdx.x;
  const int wgid = ((nwg & 7) == 0) ? ((wg & 7) * (nwg >> 3) + (wg >> 3)) : wg;

  const int nbn = N / 256;
  const int tm = wgid / nbn;
  const int tn = wgid % nbn;

  const i8* GA = A + (size_t)tm * 256 * K;
  const i8* GB = B + (size_t)tn * 256 * K;

  // swizzled ds_read byte offsets (row stride 64B, 16B granule involution):
  // chunk' = (chunk ^ (row>>1)&3), row bits 1-2 come from l31 only.
  const int key = (l31 >> 1) & 3;
  const int colx = ((l5 ^ key) << 4);              // ks=0 chunk; ks=1 = ^0x20
  const int abase = (wm * 128 + l31) * 64 + colx;  // + mi*2048 (32 rows)
  const int bbase = (wn * 64 + l31) * 64 + colx;   // + ni*2048

  i32x16 acc[4][2];
#pragma unroll
  for (int i = 0; i < 4; ++i)
#pragma unroll
    for (int j = 0; j < 2; ++j)
#pragma unroll
      for (int q = 0; q < 16; ++q) acc[i][j][q] = 0;

  const int NTI = K / 128;

  i32x4 Af[4], Bf[2];

  i8* const SM0 = &SM[0][0];
  i8* const SM1 = &SM[1][0];

  // ---- prologue: stage iter 0 fully into buf0; retire its s0 half ----
  stage_unit(GA, K, 0,  SM0,         0, wave, lane);
  stage_unit(GA, K, 0,  SM0,         1, wave, lane);
  stage_unit(GB, K, 0,  SM0 + 32768, 0, wave, lane);
  stage_unit(GB, K, 0,  SM0 + 32768, 1, wave, lane);
  stage_unit(GA, K, 64, SM0 + 16384, 0, wave, lane);
  stage_unit(GA, K, 64, SM0 + 16384, 1, wave, lane);
  stage_unit(GB, K, 64, SM0 + 49152, 0, wave, lane);
  stage_unit(GB, K, 64, SM0 + 49152, 1, wave, lane);
  VMCNT4;   // s0 A+B landed; s1's 4 still in flight (covered by p1's VMCNT4)
  BAR;

  for (int t = 0; t < NTI; t += 2) {
    DO_ITER(t,     SM0, SM1);
    DO_ITER(t + 1, SM1, SM0);
  }

  // ---- epilogue: C = acc * alpha[col]/32 + bias[col] (nontemporal) ----
  // C/D map (32x32): col = lane&31, row = (r&3) + 8*(r>>2) + 4*(lane>>5).
  const int r0 = tm * 256 + wm * 128 + 4 * l5;
  const int c0 = tn * 256 + wn * 64 + l31;
#pragma unroll
  for (int ni = 0; ni < 2; ++ni) {
    const int col = c0 + ni * 32;
    const float al = alpha[col] * INV_XSCALE;
    const float bi = bias[col];
#pragma unroll
    for (int mi = 0; mi < 4; ++mi) {
#pragma unroll
      for (int r = 0; r < 16; ++r) {
        const int row = r0 + mi * 32 + (r & 3) + 8 * (r >> 2);
        __builtin_nontemporal_store((float)acc[mi][ni][r] * al + bi,
                                    &C[(size_t)row * N + col]);
      }
    }
  }
}

// ---------------- fallback (insurance: ws too small / bad dims) ----------------

__global__ __launch_bounds__(256) void naive_kernel(
    const float* __restrict__ x, const float* __restrict__ w,
    const float* __restrict__ alpha, const float* __restrict__ bias,
    float* __restrict__ out, int M, int N, int K) {
  long idx = (long)blockIdx.x * blockDim.x + threadIdx.x;
  const long total = (long)M * N;
  const long stride = (long)gridDim.x * blockDim.x;
  for (; idx < total; idx += stride) {
    const int m = (int)(idx / N);
    const int n = (int)(idx % N);
    const float* xr = x + (size_t)m * K;
    const float* wr = w + (size_t)n * K;
    float s = 0.0f;
    for (int k = 0; k < K; ++k) {
      const float wv = wr[k];
      const float sg = (wv > 0.0f) ? 1.0f : ((wv < 0.0f) ? -1.0f : 0.0f);
      s += xr[k] * sg;
    }
    out[idx] = s * alpha[n] + bias[n];
  }
}

// ---------------- launcher ----------------

extern "C" void kernel_launch(void* const* d_in, const int* in_sizes, int n_in,
                              void* d_out, int out_size, void* d_ws, size_t ws_size,
                              hipStream_t stream) {
  const float* x = (const float*)d_in[0];
  const float* w = (const float*)d_in[1];
  const float* alpha = (const float*)d_in[2];
  const float* bias = (const float*)d_in[3];
  float* out = (float*)d_out;

  const int OUT = in_sizes[3];                // bias length
  const int IN = in_sizes[1] / OUT;           // weight is [OUT][IN]
  const int M = in_sizes[0] / IN;             // x is [B][IN]
  const int N = OUT, K = IN;

  const size_t xbytes = (size_t)M * K;        // i8
  const size_t wbytes = (size_t)N * K;        // i8
  // NTI = K/128 must be >= 2 and even (dbuf unroll-2) -> K % 256 == 0.
  const bool ok = (ws_size >= xbytes + wbytes) &&
                  (M % 256 == 0) && (N % 256 == 0) && (K % 256 == 0) &&
                  (K >= 256);

  if (!ok) {
    naive_kernel<<<2048, 256, 0, stream>>>(x, w, alpha, bias, out, M, N, K);
    return;
  }

  i8* xb = (i8*)d_ws;
  i8* wb = xb + xbytes;

  cvt_x_kernel<<<2048, 256, 0, stream>>>(x, (i32x4*)xb, (int)((size_t)M * K / 16));
  cvt_w_kernel<<<2048, 256, 0, stream>>>(w, (i32x4*)wb, (int)((size_t)N * K / 16));

  const int grid = (M / 256) * (N / 256);
  bingemm256_kernel<<<grid, 512, 0, stream>>>(xb, wb, alpha, bias, out, M, N, K);
}